// Round 6
// baseline (317.776 us; speedup 1.0000x reference)
//
#include <hip/hip_runtime.h>
#include <hip/hip_bf16.h>

typedef unsigned char u8;
typedef unsigned short u16;
typedef unsigned int u32;
typedef int i32x4 __attribute__((ext_vector_type(4)));
typedef int i32x8 __attribute__((ext_vector_type(8)));
typedef float f32x4 __attribute__((ext_vector_type(4)));

#define NX 8192
#define NY 8192
#define D  512
#define BM 128
#define BN 128
#define BK 128   // fp8 bytes per K-tile; one 16x16x128 MFMA spans it

#define SCALE_ONE 0x7F7F7F7F  // E8M0 127 = 2^0 in every byte -> any opsel picks 1.0

// async global->LDS, 16B per lane. LDS dst is wave-uniform base + lane*16.
__device__ __forceinline__ void async16(void* lds, const void* g) {
    __builtin_amdgcn_global_load_lds(
        (const __attribute__((address_space(1))) void*)g,
        (__attribute__((address_space(3))) void*)lds,
        16, 0, 0);
}

// One WAVE per row (16384 rows: first 8192 = x, rest = y). No LDS, no barrier.
// fp32 -> fp8 e4m3 (HW cvt) into ws + exact fp32 squared row norm.
__global__ __launch_bounds__(256) void prep_kernel(
    const float* __restrict__ x, const float* __restrict__ y,
    u8* __restrict__ xq, u8* __restrict__ yq,
    float* __restrict__ x2, float* __restrict__ y2)
{
    const int lane = threadIdx.x & 63;
    const int row  = blockIdx.x * 4 + (threadIdx.x >> 6);
    const float* src; u8* dst; float* nrm;
    if (row < NX) {
        src = x + (size_t)row * D; dst = xq + (size_t)row * D; nrm = x2 + row;
    } else {
        const int r = row - NX;
        src = y + (size_t)r * D; dst = yq + (size_t)r * D; nrm = y2 + r;
    }
    // 512 cols / 64 lanes = 8 per lane (two float4)
    float4 v0 = *(const float4*)(src + lane * 8);
    float4 v1 = *(const float4*)(src + lane * 8 + 4);
    float s = v0.x*v0.x + v0.y*v0.y + v0.z*v0.z + v0.w*v0.w
            + v1.x*v1.x + v1.y*v1.y + v1.z*v1.z + v1.w*v1.w;
    u32 p0 = 0, p1 = 0;
    p0 = __builtin_amdgcn_cvt_pk_fp8_f32(v0.x, v0.y, p0, false);
    p0 = __builtin_amdgcn_cvt_pk_fp8_f32(v0.z, v0.w, p0, true);
    p1 = __builtin_amdgcn_cvt_pk_fp8_f32(v1.x, v1.y, p1, false);
    p1 = __builtin_amdgcn_cvt_pk_fp8_f32(v1.z, v1.w, p1, true);
    uint2 pk = make_uint2(p0, p1);
    *(uint2*)(dst + lane * 8) = pk;

    #pragma unroll
    for (int o = 32; o > 0; o >>= 1) s += __shfl_down(s, o);
    if (lane == 0) *nrm = s;
}

// 128x128 tile, BK=128 fp8, 4 waves (2x2 of 64x64), mfma_scale 16x16x128 f8f6f4
// with unit scales. Double-buffered prefetch (stage(t+1) before compute(t),
// one __syncthreads per K-iter) + T2 both-sides XOR swizzle:
//   physical LDS layout  P(r,b) = r*128 + (b ^ ((r&7)<<4))   (16B granularity)
//   stage: LDS dest linear (global_load_lds requirement), global source col
//          pre-swizzled: lane l of a 1024B chunk reads col ((l&7)^(l>>3))*16
//   read:  fragment halves at r*128 + (ko ^ ((r&7)<<4)) and ^16, reassembled
//          in logical k order. Balanced over all 32 banks (was 16 lanes on a
//          4-bank window -> ~2x LDS read throughput).
__global__ __launch_bounds__(256) void rbf_kernel(
    const u8* __restrict__ xq, const u8* __restrict__ yq,
    const float* __restrict__ x2, const float* __restrict__ y2,
    const float* __restrict__ gamma_p, float* __restrict__ out)
{
    __shared__ u8 As[2][BM * BK];   // 2 x 16 KiB
    __shared__ u8 Bs[2][BN * BK];   // 2 x 16 KiB

    const int t    = threadIdx.x;
    const int lane = t & 63;
    const int wid  = t >> 6;          // 0..3
    const int wr   = wid >> 1;        // row half
    const int wc   = wid & 1;         // col half

    // XCD-aware bijective swizzle (nwg = 4096, % 8 == 0)
    const int nwg = gridDim.x;
    const int cpx = nwg >> 3;
    const int bid = blockIdx.x;
    const int swz = (bid & 7) * cpx + (bid >> 3);
    const int brow = swz >> 6;        // 64 x 64 tile grid
    const int bcol = swz & 63;

    const size_t row0 = (size_t)brow * BM;
    const size_t col0 = (size_t)bcol * BN;

    // staging: chunk = 1024 B = 8 rows x 128 B. 16 chunks/tile, wave stages 4.
    // Global col pre-swizzled so linear LDS writes realize layout P(r,b).
    const int c0 = wid * 4;
    const int lr = lane >> 3;
    const int lc = ((lane & 7) ^ lr) * 16;   // inverse-swizzled source col-byte

    auto stage = [&](int buf, int kt) {
        #pragma unroll
        for (int i = 0; i < 4; ++i) {
            const int c = c0 + i;
            async16(&As[buf][c * 1024], xq + (row0 + (size_t)(c * 8 + lr)) * D + kt + lc);
        }
        #pragma unroll
        for (int i = 0; i < 4; ++i) {
            const int c = c0 + i;
            async16(&Bs[buf][c * 1024], yq + (col0 + (size_t)(c * 8 + lr)) * D + kt + lc);
        }
    };

    stage(0, 0);
    __syncthreads();   // prologue drain: tile 0 in LDS

    f32x4 acc[4][4] = {};
    const int ar = (lane & 15);
    const int ko = (lane >> 4) * 32;
    const int o0 = ko ^ ((ar & 7) << 4);   // swizzled low-half col offset (r&7 == ar&7)
    const int o1 = o0 ^ 16;                // high half

    #pragma unroll
    for (int kt = 0; kt < 4; ++kt) {
        if (kt < 3) stage((kt + 1) & 1, (kt + 1) * BK);   // prefetch next tile
        const int cur = kt & 1;
        i32x8 a[4], b[4];
        #pragma unroll
        for (int m = 0; m < 4; ++m) {
            const u8* base = &As[cur][(wr * 64 + m * 16 + ar) * BK];
            i32x4 lo = *(const i32x4*)(base + o0);
            i32x4 hi = *(const i32x4*)(base + o1);
            a[m] = (i32x8){lo[0], lo[1], lo[2], lo[3], hi[0], hi[1], hi[2], hi[3]};
        }
        #pragma unroll
        for (int n = 0; n < 4; ++n) {
            const u8* base = &Bs[cur][(wc * 64 + n * 16 + ar) * BK];
            i32x4 lo = *(const i32x4*)(base + o0);
            i32x4 hi = *(const i32x4*)(base + o1);
            b[n] = (i32x8){lo[0], lo[1], lo[2], lo[3], hi[0], hi[1], hi[2], hi[3]};
        }
        #pragma unroll
        for (int m = 0; m < 4; ++m)
            #pragma unroll
            for (int n = 0; n < 4; ++n)
                acc[m][n] = __builtin_amdgcn_mfma_scale_f32_16x16x128_f8f6f4(
                    a[m], b[n], acc[m][n],
                    0 /*A=fp8*/, 0 /*B=fp8*/,
                    0, SCALE_ONE, 0, SCALE_ONE);
        if (kt < 3) __syncthreads();   // drains prefetch (vmcnt) + read-done (lgkm)
    }

    // epilogue: out[i][j] = exp(-gamma * max(x2[i] + y2[j] - 2*dot, 0))
    // nontemporal: 268 MB write-once stream must not evict input panels from L2
    const float gamma = *gamma_p;
    const int rl = (lane >> 4) * 4;   // C/D: row = (lane>>4)*4 + reg, col = lane&15
    const int cl = lane & 15;
    #pragma unroll
    for (int m = 0; m < 4; ++m) {
        #pragma unroll
        for (int j = 0; j < 4; ++j) {
            const size_t gr = row0 + wr * 64 + m * 16 + rl + j;
            const float xn = x2[gr];
            float* orow = out + gr * (size_t)NY + col0 + wc * 64 + cl;
            #pragma unroll
            for (int n = 0; n < 4; ++n) {
                const float yn = y2[col0 + wc * 64 + n * 16 + cl];
                float sq = xn + yn - 2.0f * acc[m][n][j];
                sq = fmaxf(sq, 0.0f);
                __builtin_nontemporal_store(__expf(-gamma * sq), &orow[n * 16]);
            }
        }
    }
}

extern "C" void kernel_launch(void* const* d_in, const int* in_sizes, int n_in,
                              void* d_out, int out_size, void* d_ws, size_t ws_size,
                              hipStream_t stream) {
    const float* x = (const float*)d_in[0];
    const float* y = (const float*)d_in[1];
    const float* gamma_p = (const float*)d_in[2];
    float* out = (float*)d_out;

    // ws layout: xq[8192*512] u8 | yq[8192*512] u8 | x2[8192] f32 | y2[8192] f32
    u8* xq = (u8*)d_ws;
    u8* yq = xq + (size_t)NX * D;
    float* x2 = (float*)(yq + (size_t)NY * D);
    float* y2 = x2 + NX;

    prep_kernel<<<(NX + NY) / 4, 256, 0, stream>>>(x, y, xq, yq, x2, y2);

    const int grid = (NX / BM) * (NY / BN);   // 64 * 64 = 4096
    rbf_kernel<<<grid, 256, 0, stream>>>(xq, yq, x2, y2, gamma_p, out);
}